// Round 1
// baseline (206.128 us; speedup 1.0000x reference)
//
#include <hip/hip_runtime.h>

// YOLO loss: input [B,30,7,7] f32, target [B,7,7,30] f32 -> scalar f32.
//
// Round 4: fix the target-load coalescing. rocprof showed VALUBusy 8%,
// HBM 18.6%, occupancy 51% -> request-bound, not BW-bound. The 15 float2
// target loads/thread at per-lane stride 120B touch ~60 cache lines per
// wave-instruction (~8x request amplification on half the traffic).
// Fix: each block's target slice is CONTIGUOUS (256 rows x 30 floats,
// 16B-aligned base) -> stage it into LDS with coalesced float4 loads
// (16B/lane = 1KB/wave-instr), then read rows from LDS. Input loads
// (already lane-contiguous per channel instruction) stay direct and are
// issued before the barrier so they drain under the staging latency.

#define NCH    30
#define CELLS  49
#define TPB    256
#define IMGSZ  448.0f
#define CELLSZ 64.0f

__device__ __forceinline__ float iou_f(float ax1, float ay1, float ax2, float ay2,
                                       float bx1, float by1, float bx2, float by2) {
    float l  = fmaxf(ax1, bx1);
    float r  = fminf(ax2, bx2);
    float t  = fmaxf(ay1, by1);
    float bo = fminf(ay2, by2);
    bool  m  = (l < r) && (t < bo);
    float inter = (r - l) * (bo - t);
    float uni   = (ax2 - ax1) * (ay2 - ay1) + (bx2 - bx1) * (by2 - by1);
    float denom = uni - inter;
    return m ? (inter / denom) : 0.0f;
}

__device__ __forceinline__ void decode_box(float p0, float p1, float p2, float p3,
                                           float gx, float gy,
                                           float& x1, float& y1, float& x2, float& y2) {
    float cx = p0 * CELLSZ + gx;
    float cy = p1 * CELLSZ + gy;
    float w  = p2 * IMGSZ;
    float h  = p3 * IMGSZ;
    x1 = fminf(fmaxf(cx - w * 0.5f, 0.0f), IMGSZ);
    y1 = fminf(fmaxf(cy - h * 0.5f, 0.0f), IMGSZ);
    x2 = fminf(fmaxf(cx + w * 0.5f, 0.0f), IMGSZ);
    y2 = fminf(fmaxf(cy + h * 0.5f, 0.0f), IMGSZ);
}

__global__ __launch_bounds__(TPB, 4) void yolo_loss_kernel(
        const float* __restrict__ input,   // [B,30,7,7]
        const float* __restrict__ target,  // [B,7,7,30] == [N,30]
        float* __restrict__ out,
        int ncells) {
    __shared__ float red[TPB / 64];
    __shared__ __align__(16) float smt[TPB * NCH];   // 30720 B target tile

    const int tid = threadIdx.x;
    const int n0  = blockIdx.x * TPB;
    const int n   = n0 + tid;

    // ---- coalesced target staging: block slice is contiguous [TPB*NCH] ----
    {
        const int rows = min(TPB, ncells - n0);      // full blocks here (N % 256 == 0)
        const int nf4  = (rows * NCH) >> 2;          // rows even -> exact float4 count
        const float4* __restrict__ tp4 =
            reinterpret_cast<const float4*>(target + (size_t)n0 * NCH);
        float4* sm4 = reinterpret_cast<float4*>(smt);
        if (nf4 == (TPB * NCH) / 4) {                // 1920 float4
            #pragma unroll
            for (int k = 0; k < (TPB * NCH) / 4 / TPB; ++k)          // 7 full rounds
                sm4[tid + k * TPB] = tp4[tid + k * TPB];
            if (tid < (TPB * NCH) / 4 - ((TPB * NCH) / 4 / TPB) * TPB)  // 128 tail
                sm4[((TPB * NCH) / 4 / TPB) * TPB + tid] =
                    tp4[((TPB * NCH) / 4 / TPB) * TPB + tid];
        } else {
            for (int i = tid; i < nf4; i += TPB) sm4[i] = tp4[i];
            for (int i = nf4 * 4 + tid; i < rows * NCH; i += TPB)
                smt[i] = target[(size_t)n0 * NCH + i];
        }
    }

    // ---- issue all 30 input loads before the barrier (drain under staging) ----
    const bool active = (n < ncells);
    float x[NCH];
    float gx = 0.0f, gy = 0.0f;
    if (active) {
        const int b    = n / CELLS;
        const int cell = n - b * CELLS;
        const float* __restrict__ ip = input + (size_t)b * (NCH * CELLS) + cell;
        #pragma unroll
        for (int c = 0; c < NCH; ++c) x[c] = ip[c * CELLS];
        const int row = cell / 7;
        const int col = cell - row * 7;
        gx = (float)col * CELLSZ;
        gy = (float)row * CELLSZ;
    }

    __syncthreads();

    float loss = 0.0f;
    if (active) {
        const float* trow = smt + tid * NCH;
        float tl[NCH];
        #pragma unroll
        for (int k = 0; k < NCH / 2; ++k) {
            float2 v = *reinterpret_cast<const float2*>(trow + 2 * k);
            tl[2 * k]     = v.x;
            tl[2 * k + 1] = v.y;
        }

        float p0x1, p0y1, p0x2, p0y2, p1x1, p1y1, p1x2, p1y2;
        decode_box(x[0], x[1], x[2], x[3], gx, gy, p0x1, p0y1, p0x2, p0y2);
        decode_box(x[5], x[6], x[7], x[8], gx, gy, p1x1, p1y1, p1x2, p1y2);
        float t0x1, t0y1, t0x2, t0y2, t1x1, t1y1, t1x2, t1y2;
        decode_box(tl[0], tl[1], tl[2], tl[3], gx, gy, t0x1, t0y1, t0x2, t0y2);
        decode_box(tl[5], tl[6], tl[7], tl[8], gx, gy, t1x1, t1y1, t1x2, t1y2);

        float iou1 = iou_f(p0x1, p0y1, p0x2, p0y2, t0x1, t0y1, t0x2, t0y2);
        float iou2 = iou_f(p1x1, p1y1, p1x2, p1y2, t1x1, t1y1, t1x2, t1y2);

        bool  mask = iou1 < iou2;
        float iou  = mask ? iou2 : iou1;
        float s0 = mask ? x[5] : x[0];
        float s1 = mask ? x[6] : x[1];
        float s2 = mask ? x[7] : x[2];
        float s3 = mask ? x[8] : x[3];
        float s4 = mask ? x[9] : x[4];

        float w = (tl[4] == 1.0f) ? 1.0f : 0.0f;

        float d0 = s0 - tl[0];
        float d1 = s1 - tl[1];
        float coord = d0 * d0 + d1 * d1;

        float ds2 = sqrtf(s2) - sqrtf(tl[2]);
        float ds3 = sqrtf(s3) - sqrtf(tl[3]);
        float size = ds2 * ds2 + ds3 * ds3;

        float dc = s4 - iou;
        float conf = dc * dc;
        float noobj = s4 * s4;

        float cls = 0.0f;
        #pragma unroll
        for (int c = 10; c < NCH; ++c) {
            float d = x[c] - tl[c];
            cls += d * d;
        }

        loss = w * (5.0f * (coord + size) + conf + cls) + 0.5f * (1.0f - w) * noobj;
    }

    // Wave reduce (64 lanes), then block reduce, one atomic per block.
    #pragma unroll
    for (int off = 32; off > 0; off >>= 1)
        loss += __shfl_down(loss, off, 64);

    const int wid  = tid >> 6;
    const int lane = tid & 63;
    if (lane == 0) red[wid] = loss;
    __syncthreads();
    if (tid == 0) {
        float s = 0.0f;
        #pragma unroll
        for (int i = 0; i < TPB / 64; ++i) s += red[i];
        atomicAdd(out, s);
    }
}

extern "C" void kernel_launch(void* const* d_in, const int* in_sizes, int n_in,
                              void* d_out, int out_size, void* d_ws, size_t ws_size,
                              hipStream_t stream) {
    const float* input  = (const float*)d_in[0];   // [B,30,7,7]
    const float* target = (const float*)d_in[1];   // [B,7,7,30]
    float* out = (float*)d_out;

    const int ncells = in_sizes[0] / NCH;          // B*49 = 802816
    const int blocks = (ncells + TPB - 1) / TPB;   // 3136

    // d_out is poisoned 0xAA before every timed launch -> zero it (capture-safe).
    hipMemsetAsync(d_out, 0, sizeof(float), stream);
    yolo_loss_kernel<<<blocks, TPB, 0, stream>>>(input, target, out, ncells);
}

// Round 2
// 205.948 us; speedup vs baseline: 1.0009x; 1.0009x over previous
//
#include <hip/hip_runtime.h>

// YOLO loss: input [B,30,7,7] f32, target [B,7,7,30] f32 -> scalar f32.
//
// Round 5: kill the same-address atomic chain. Evidence: dur pinned at
// ~71 us across (a) direct loads, (b) LDS-staged coalesced loads, and
// (c) an L3-warm pass with near-zero HBM fetch. Duration is cache- and
// memory-pattern-independent => fixed cost. 3136 blocks x atomicAdd to
// ONE address = serialized device-scope RMW chain: 71us/3136 = 22.6 ns
// = ~54 cycles per atomic. Fix: per-block partials to d_ws (plain
// stores, no contention) + a tiny 1-block reduce kernel. Atomic path
// kept only as a ws_size fallback.

#define NCH    30
#define CELLS  49
#define TPB    256
#define IMGSZ  448.0f
#define CELLSZ 64.0f

__device__ __forceinline__ float iou_f(float ax1, float ay1, float ax2, float ay2,
                                       float bx1, float by1, float bx2, float by2) {
    float l  = fmaxf(ax1, bx1);
    float r  = fminf(ax2, bx2);
    float t  = fmaxf(ay1, by1);
    float bo = fminf(ay2, by2);
    bool  m  = (l < r) && (t < bo);
    float inter = (r - l) * (bo - t);
    float uni   = (ax2 - ax1) * (ay2 - ay1) + (bx2 - bx1) * (by2 - by1);
    float denom = uni - inter;
    return m ? (inter / denom) : 0.0f;
}

__device__ __forceinline__ void decode_box(float p0, float p1, float p2, float p3,
                                           float gx, float gy,
                                           float& x1, float& y1, float& x2, float& y2) {
    float cx = p0 * CELLSZ + gx;
    float cy = p1 * CELLSZ + gy;
    float w  = p2 * IMGSZ;
    float h  = p3 * IMGSZ;
    x1 = fminf(fmaxf(cx - w * 0.5f, 0.0f), IMGSZ);
    y1 = fminf(fmaxf(cy - h * 0.5f, 0.0f), IMGSZ);
    x2 = fminf(fmaxf(cx + w * 0.5f, 0.0f), IMGSZ);
    y2 = fminf(fmaxf(cy + h * 0.5f, 0.0f), IMGSZ);
}

__device__ __forceinline__ float cell_loss(const float* __restrict__ input,
                                           const float* __restrict__ target,
                                           int n) {
    const int b    = n / CELLS;
    const int cell = n - b * CELLS;

    // issue all 45 loads up front
    const float2* __restrict__ tp =
        reinterpret_cast<const float2*>(target) + (long long)n * 15;
    const float* __restrict__ ip = input + (size_t)b * (NCH * CELLS) + cell;

    float2 tv[15];
    float  x[NCH];
    #pragma unroll
    for (int k = 0; k < 15; ++k) tv[k] = tp[k];
    #pragma unroll
    for (int c = 0; c < NCH; ++c) x[c] = ip[c * CELLS];

    float tl[NCH];
    #pragma unroll
    for (int k = 0; k < 15; ++k) { tl[2 * k] = tv[k].x; tl[2 * k + 1] = tv[k].y; }

    const int row  = cell / 7;
    const int col  = cell - row * 7;
    const float gx = (float)col * CELLSZ;
    const float gy = (float)row * CELLSZ;

    float p0x1, p0y1, p0x2, p0y2, p1x1, p1y1, p1x2, p1y2;
    decode_box(x[0], x[1], x[2], x[3], gx, gy, p0x1, p0y1, p0x2, p0y2);
    decode_box(x[5], x[6], x[7], x[8], gx, gy, p1x1, p1y1, p1x2, p1y2);
    float t0x1, t0y1, t0x2, t0y2, t1x1, t1y1, t1x2, t1y2;
    decode_box(tl[0], tl[1], tl[2], tl[3], gx, gy, t0x1, t0y1, t0x2, t0y2);
    decode_box(tl[5], tl[6], tl[7], tl[8], gx, gy, t1x1, t1y1, t1x2, t1y2);

    float iou1 = iou_f(p0x1, p0y1, p0x2, p0y2, t0x1, t0y1, t0x2, t0y2);
    float iou2 = iou_f(p1x1, p1y1, p1x2, p1y2, t1x1, t1y1, t1x2, t1y2);

    bool  mask = iou1 < iou2;
    float iou  = mask ? iou2 : iou1;
    float s0 = mask ? x[5] : x[0];
    float s1 = mask ? x[6] : x[1];
    float s2 = mask ? x[7] : x[2];
    float s3 = mask ? x[8] : x[3];
    float s4 = mask ? x[9] : x[4];

    float w = (tl[4] == 1.0f) ? 1.0f : 0.0f;

    float d0 = s0 - tl[0];
    float d1 = s1 - tl[1];
    float coord = d0 * d0 + d1 * d1;

    float ds2 = sqrtf(s2) - sqrtf(tl[2]);
    float ds3 = sqrtf(s3) - sqrtf(tl[3]);
    float size = ds2 * ds2 + ds3 * ds3;

    float dc = s4 - iou;
    float conf = dc * dc;
    float noobj = s4 * s4;

    float cls = 0.0f;
    #pragma unroll
    for (int c = 10; c < NCH; ++c) {
        float d = x[c] - tl[c];
        cls += d * d;
    }

    return w * (5.0f * (coord + size) + conf + cls) + 0.5f * (1.0f - w) * noobj;
}

template <bool USE_ATOMIC>
__global__ __launch_bounds__(TPB, 4) void yolo_loss_kernel(
        const float* __restrict__ input,   // [B,30,7,7]
        const float* __restrict__ target,  // [B,7,7,30] == [N,30]
        float* __restrict__ dst,           // USE_ATOMIC ? scalar out : partials[grid]
        int ncells) {
    __shared__ float red[TPB / 64];

    const int tid = threadIdx.x;
    const int n   = blockIdx.x * TPB + tid;

    float loss = (n < ncells) ? cell_loss(input, target, n) : 0.0f;

    #pragma unroll
    for (int off = 32; off > 0; off >>= 1)
        loss += __shfl_down(loss, off, 64);

    const int wid  = tid >> 6;
    const int lane = tid & 63;
    if (lane == 0) red[wid] = loss;
    __syncthreads();
    if (tid == 0) {
        float s = 0.0f;
        #pragma unroll
        for (int i = 0; i < TPB / 64; ++i) s += red[i];
        if (USE_ATOMIC) atomicAdd(dst, s);
        else            dst[blockIdx.x] = s;
    }
}

__global__ __launch_bounds__(TPB) void reduce_kernel(
        const float* __restrict__ parts, float* __restrict__ out, int n) {
    __shared__ float red[TPB / 64];
    float s = 0.0f;
    for (int i = threadIdx.x; i < n; i += TPB) s += parts[i];
    #pragma unroll
    for (int off = 32; off > 0; off >>= 1)
        s += __shfl_down(s, off, 64);
    const int wid  = threadIdx.x >> 6;
    const int lane = threadIdx.x & 63;
    if (lane == 0) red[wid] = s;
    __syncthreads();
    if (threadIdx.x == 0) {
        float t = 0.0f;
        #pragma unroll
        for (int i = 0; i < TPB / 64; ++i) t += red[i];
        *out = t;   // plain store: overwrites poison, no memset needed
    }
}

extern "C" void kernel_launch(void* const* d_in, const int* in_sizes, int n_in,
                              void* d_out, int out_size, void* d_ws, size_t ws_size,
                              hipStream_t stream) {
    const float* input  = (const float*)d_in[0];   // [B,30,7,7]
    const float* target = (const float*)d_in[1];   // [B,7,7,30]
    float* out = (float*)d_out;

    const int ncells = in_sizes[0] / NCH;          // B*49 = 802816
    const int blocks = (ncells + TPB - 1) / TPB;   // 3136

    if (d_ws != nullptr && ws_size >= (size_t)blocks * sizeof(float)) {
        float* parts = (float*)d_ws;
        yolo_loss_kernel<false><<<blocks, TPB, 0, stream>>>(input, target, parts, ncells);
        reduce_kernel<<<1, TPB, 0, stream>>>(parts, out, blocks);
    } else {
        // fallback: d_out poisoned 0xAA before every timed launch -> zero it
        hipMemsetAsync(d_out, 0, sizeof(float), stream);
        yolo_loss_kernel<true><<<blocks, TPB, 0, stream>>>(input, target, out, ncells);
    }
}

// Round 3
// 205.180 us; speedup vs baseline: 1.0046x; 1.0037x over previous
//
#include <hip/hip_runtime.h>

// YOLO loss: input [B,30,7,7] f32, target [B,7,7,30] f32 -> scalar f32.
//
// Round 6: decouple memory-level parallelism from register pressure.
// Evidence chain: dur ~72us invariant to access pattern (r4), atomic
// removal (r5), and cache state (r0 L3-warm dispatch). All variants
// loaded through the VGPR path with compiler-chosen 40-44 VGPR =>
// ~4-8 loads in flight per wave => latency-bound at ~15 cyc/line
// (need ~1-4). Fix: __builtin_amdgcn_global_load_lds — async DMA
// global->LDS, zero data VGPRs, up to 63 outstanding per wave. Stage
// BOTH tensors per block (target: exact contiguous 30KB slice; input:
// contiguous batch-span, even-batch base for 16B alignment), one
// barrier (compiler emits the vmcnt(0) drain), compute from LDS.

#define NCH    30
#define CELLS  49
#define TPB    256
#define IMGSZ  448.0f
#define CELLSZ 64.0f
#define BPC    (NCH * CELLS)          // 1470 floats per batch of input

// LDS buffers (floats). Input: worst span = 8 batches = 47040 B, staged in
// 16B units by whole waves -> pad to 46 chunks * 1024 B = 47104 B.
#define SMI_FLOATS 11776
#define SMT_FLOATS (TPB * NCH)        // 30720 B, exactly 30 wave-chunks

typedef const __attribute__((address_space(1))) unsigned int* gp_t;
typedef __attribute__((address_space(3))) unsigned int* lp_t;

__device__ __forceinline__ void gload16(const void* g, void* l) {
    // 16B per lane; LDS dest = readfirstlane(l) + lane*16 (lane-linear copy)
    __builtin_amdgcn_global_load_lds((gp_t)g, (lp_t)l, 16, 0, 0);
}

__device__ __forceinline__ float iou_f(float ax1, float ay1, float ax2, float ay2,
                                       float bx1, float by1, float bx2, float by2) {
    float l  = fmaxf(ax1, bx1);
    float r  = fminf(ax2, bx2);
    float t  = fmaxf(ay1, by1);
    float bo = fminf(ay2, by2);
    bool  m  = (l < r) && (t < bo);
    float inter = (r - l) * (bo - t);
    float uni   = (ax2 - ax1) * (ay2 - ay1) + (bx2 - bx1) * (by2 - by1);
    float denom = uni - inter;
    return m ? (inter / denom) : 0.0f;
}

__device__ __forceinline__ void decode_box(float p0, float p1, float p2, float p3,
                                           float gx, float gy,
                                           float& x1, float& y1, float& x2, float& y2) {
    float cx = p0 * CELLSZ + gx;
    float cy = p1 * CELLSZ + gy;
    float w  = p2 * IMGSZ;
    float h  = p3 * IMGSZ;
    x1 = fminf(fmaxf(cx - w * 0.5f, 0.0f), IMGSZ);
    y1 = fminf(fmaxf(cy - h * 0.5f, 0.0f), IMGSZ);
    x2 = fminf(fmaxf(cx + w * 0.5f, 0.0f), IMGSZ);
    y2 = fminf(fmaxf(cy + h * 0.5f, 0.0f), IMGSZ);
}

template <bool USE_ATOMIC>
__global__ __launch_bounds__(TPB) void yolo_loss_kernel(
        const float* __restrict__ input,   // [B,30,7,7]
        const float* __restrict__ target,  // [B,7,7,30] == [N,30]
        float* __restrict__ dst,           // USE_ATOMIC ? scalar : partials[grid]
        int ncells) {
    __shared__ float red[TPB / 64];
    __shared__ __align__(16) float smi[SMI_FLOATS];
    __shared__ __align__(16) float smt[SMT_FLOATS];

    const int tid  = threadIdx.x;
    const int n0   = blockIdx.x * TPB;
    const int rows = min(TPB, ncells - n0);
    const int wid  = tid >> 6;
    const int lane = tid & 63;

    // ---- input batch span (contiguous in memory; even base => 16B aligned) ----
    const int b_lo = n0 / CELLS;
    const int b_hi = (n0 + rows - 1) / CELLS;
    const int b0   = b_lo & ~1;                       // b0*1470*4 % 16 == 0
    const size_t in_base = (size_t)b0 * BPC;          // float index
    const int span_fl = (b_hi - b0 + 1) * BPC;        // floats (may be %4 == 2)
    const int n16i    = span_fl >> 2;                 // whole 16B units (floor)

    const size_t tg_base = (size_t)n0 * NCH;
    const int tfl  = rows * NCH;
    const int n16t = tfl >> 2;                        // floor

    // ---- async DMA staging; per-wave lane-linear chunks of 1KB ----
    const int ct = (n16t + 63) >> 6;                  // 30 when rows==256
    const int ci = (n16i + 63) >> 6;                  // <=46
    for (int c = wid; c < ct; c += TPB / 64) {
        int i  = c * 64 + lane;                       // LDS slot (lane-determined)
        int ig = min(i, n16t - 1);                    // clamp global only
        gload16(target + tg_base + (size_t)ig * 4, (char*)smt + (size_t)i * 16);
    }
    for (int c = wid; c < ci; c += TPB / 64) {
        int i  = c * 64 + lane;
        int ig = min(i, n16i - 1);
        gload16(input + in_base + (size_t)ig * 4, (char*)smi + (size_t)i * 16);
    }
    // scalar tails (span % 16B != 0)
    if ((span_fl & 3) && tid < (span_fl & 3))
        smi[(n16i << 2) + tid] = input[in_base + (n16i << 2) + tid];
    if ((tfl & 3) && tid < (tfl & 3))
        smt[(n16t << 2) + tid] = target[tg_base + (n16t << 2) + tid];

    __syncthreads();   // compiler emits s_waitcnt vmcnt(0) before s_barrier

    float loss = 0.0f;
    if (tid < rows) {
        const int n    = n0 + tid;
        const int b    = n / CELLS;
        const int cell = n - b * CELLS;

        const float* ip = smi + (b - b0) * BPC + cell;
        float x[NCH];
        #pragma unroll
        for (int c = 0; c < NCH; ++c) x[c] = ip[c * CELLS];

        const float* trow = smt + tid * NCH;
        float tl[NCH];
        #pragma unroll
        for (int k = 0; k < NCH / 2; ++k) {
            float2 v = *reinterpret_cast<const float2*>(trow + 2 * k);
            tl[2 * k]     = v.x;
            tl[2 * k + 1] = v.y;
        }

        const int row  = cell / 7;
        const int col  = cell - row * 7;
        const float gx = (float)col * CELLSZ;
        const float gy = (float)row * CELLSZ;

        float p0x1, p0y1, p0x2, p0y2, p1x1, p1y1, p1x2, p1y2;
        decode_box(x[0], x[1], x[2], x[3], gx, gy, p0x1, p0y1, p0x2, p0y2);
        decode_box(x[5], x[6], x[7], x[8], gx, gy, p1x1, p1y1, p1x2, p1y2);
        float t0x1, t0y1, t0x2, t0y2, t1x1, t1y1, t1x2, t1y2;
        decode_box(tl[0], tl[1], tl[2], tl[3], gx, gy, t0x1, t0y1, t0x2, t0y2);
        decode_box(tl[5], tl[6], tl[7], tl[8], gx, gy, t1x1, t1y1, t1x2, t1y2);

        float iou1 = iou_f(p0x1, p0y1, p0x2, p0y2, t0x1, t0y1, t0x2, t0y2);
        float iou2 = iou_f(p1x1, p1y1, p1x2, p1y2, t1x1, t1y1, t1x2, t1y2);

        bool  mask = iou1 < iou2;
        float iou  = mask ? iou2 : iou1;
        float s0 = mask ? x[5] : x[0];
        float s1 = mask ? x[6] : x[1];
        float s2 = mask ? x[7] : x[2];
        float s3 = mask ? x[8] : x[3];
        float s4 = mask ? x[9] : x[4];

        float w = (tl[4] == 1.0f) ? 1.0f : 0.0f;

        float d0 = s0 - tl[0];
        float d1 = s1 - tl[1];
        float coord = d0 * d0 + d1 * d1;

        float ds2 = sqrtf(s2) - sqrtf(tl[2]);
        float ds3 = sqrtf(s3) - sqrtf(tl[3]);
        float size = ds2 * ds2 + ds3 * ds3;

        float dc = s4 - iou;
        float conf = dc * dc;
        float noobj = s4 * s4;

        float cls = 0.0f;
        #pragma unroll
        for (int c = 10; c < NCH; ++c) {
            float d = x[c] - tl[c];
            cls += d * d;
        }

        loss = w * (5.0f * (coord + size) + conf + cls) + 0.5f * (1.0f - w) * noobj;
    }

    #pragma unroll
    for (int off = 32; off > 0; off >>= 1)
        loss += __shfl_down(loss, off, 64);

    if (lane == 0) red[wid] = loss;
    __syncthreads();
    if (tid == 0) {
        float s = 0.0f;
        #pragma unroll
        for (int i = 0; i < TPB / 64; ++i) s += red[i];
        if (USE_ATOMIC) atomicAdd(dst, s);
        else            dst[blockIdx.x] = s;
    }
}

__global__ __launch_bounds__(TPB) void reduce_kernel(
        const float* __restrict__ parts, float* __restrict__ out, int n) {
    __shared__ float red[TPB / 64];
    float s = 0.0f;
    for (int i = threadIdx.x; i < n; i += TPB) s += parts[i];
    #pragma unroll
    for (int off = 32; off > 0; off >>= 1)
        s += __shfl_down(s, off, 64);
    const int wid  = threadIdx.x >> 6;
    const int lane = threadIdx.x & 63;
    if (lane == 0) red[wid] = s;
    __syncthreads();
    if (threadIdx.x == 0) {
        float t = 0.0f;
        #pragma unroll
        for (int i = 0; i < TPB / 64; ++i) t += red[i];
        *out = t;   // plain store overwrites poison; no memset needed
    }
}

extern "C" void kernel_launch(void* const* d_in, const int* in_sizes, int n_in,
                              void* d_out, int out_size, void* d_ws, size_t ws_size,
                              hipStream_t stream) {
    const float* input  = (const float*)d_in[0];   // [B,30,7,7]
    const float* target = (const float*)d_in[1];   // [B,7,7,30]
    float* out = (float*)d_out;

    const int ncells = in_sizes[0] / NCH;          // B*49 = 802816
    const int blocks = (ncells + TPB - 1) / TPB;   // 3136

    if (d_ws != nullptr && ws_size >= (size_t)blocks * sizeof(float)) {
        float* parts = (float*)d_ws;
        yolo_loss_kernel<false><<<blocks, TPB, 0, stream>>>(input, target, parts, ncells);
        reduce_kernel<<<1, TPB, 0, stream>>>(parts, out, blocks);
    } else {
        hipMemsetAsync(d_out, 0, sizeof(float), stream);
        yolo_loss_kernel<true><<<blocks, TPB, 0, stream>>>(input, target, out, ncells);
    }
}